// Round 13
// baseline (71.709 us; speedup 1.0000x reference)
//
#include <hip/hip_runtime.h>
#include <math.h>

// CTC forward loss, Keras ctc_batch_cost semantics.
// B=1024, T=256, C=128, L=64, S=2L+1=129, blank=C-1=127.
// Prob-domain forward DP, exact power-of-2 rescale per 8-step chunk.
// Role split per block (512 thr):
//   waves 1-5 : stream y_pred (float4, 8-deep) computing ROW SUMS ONLY;
//               log(sum) accumulated as mantissa-product + exponent-sum
//               (one __logf per wave at the end, no per-row transcendental).
//   waves 6-7 : direct-gather qtab[t][l] = yp[t*128+lab_l] from global
//               (label column is per-lane constant -> no shuffles at all),
//               plus qblank; publish progress every 8 rows.
//   wave 0    : register DP, polling gather progress. Finishes ~with gathers,
//               hidden under the streaming time. No wave ever waits on DP.
#define BATCH 1024
#define TT    256
#define CC    128
#define LL    64
#define EPSV  (1e-7f)

typedef float f32x4 __attribute__((ext_vector_type(4)));

// DPP ctrl: row_shr:N = 0x110+N, row_bcast:15 = 0x142, row_bcast:31 = 0x143,
// wave_rol:1 = 0x134.
template <int CTRL>
__device__ __forceinline__ float dpp0(float x) {   // invalid lanes -> 0
    return __int_as_float(__builtin_amdgcn_update_dpp(0, __float_as_int(x), CTRL, 0xF, 0xF, true));
}
template <int CTRL>
__device__ __forceinline__ float dppS(float x) {   // invalid lanes -> self
    return __int_as_float(__builtin_amdgcn_update_dpp(__float_as_int(x), __float_as_int(x), CTRL, 0xF, 0xF, false));
}
__device__ __forceinline__ float rol1_f(float x) { // lane i <- lane (i-1)&63
    return __int_as_float(__builtin_amdgcn_update_dpp(__float_as_int(x), __float_as_int(x), 0x134, 0xF, 0xF, false));
}
__device__ __forceinline__ int rol1_i(int x) {
    return __builtin_amdgcn_update_dpp(x, x, 0x134, 0xF, 0xF, false);
}
__device__ __forceinline__ float rdlane(float x, int l) {
    return __int_as_float(__builtin_amdgcn_readlane(__float_as_int(x), l));
}
__device__ __forceinline__ float wave_max_bcast(float m) {
    m = fmaxf(m, dppS<0x111>(m));
    m = fmaxf(m, dppS<0x112>(m));
    m = fmaxf(m, dppS<0x114>(m));
    m = fmaxf(m, dppS<0x118>(m));
    m = fmaxf(m, dppS<0x142>(m));
    m = fmaxf(m, dppS<0x143>(m));
    return rdlane(m, 63);
}
__device__ __forceinline__ unsigned short f16b(float x) { // fp32 -> fp16 bits (RTN)
    _Float16 h = (_Float16)x;
    unsigned short u; __builtin_memcpy(&u, &h, 2);
    return u;
}
__device__ __forceinline__ float h2f(unsigned short u) {
    _Float16 h; __builtin_memcpy(&h, &u, 2);
    return (float)h;
}

__global__ __launch_bounds__(512, 8) void ctc_fwd_kernel(const int* __restrict__ y_true,
                                                         const float* __restrict__ y_pred,
                                                         float* __restrict__ out) {
    __shared__ unsigned short qtab[TT][64];  // q[t][l] = p[t][yt[l]]+eps (fp16 bits)
    __shared__ float qblank[TT];             // q[t][blank]
    __shared__ float logZpart[5];            // streamer partials (waves 1..5)
    __shared__ int   gatherDone[2];          // rows completed per half
    __shared__ int   doneCnt;                // finished streamers (5 when done)

    const int b    = blockIdx.x;
    const int tid  = threadIdx.x;
    const int wv   = tid >> 6;
    const int lane = tid & 63;

    const float* yp = y_pred + (size_t)b * (TT * CC);
    const int lab  = y_true[b * LL + lane];  // lane l holds label l (< 127 always)

    if (tid < 2) gatherDone[tid] = 0;
    if (tid == 2) doneCnt = 0;
    __syncthreads();

    if (wv >= 6) {
        // ============ gather waves: wv==7 -> rows 0..127, wv==6 -> rows 128..255 ============
        const int half = (wv == 7) ? 0 : 1;
        const int t0 = half * 128;
        // qblank first (strided loads, 2 instructions)
        float b0 = yp[(size_t)(t0 + lane) * CC + 127];
        float b1 = yp[(size_t)(t0 + 64 + lane) * CC + 127];
        qblank[t0 + lane]      = b0 + EPSV;
        qblank[t0 + 64 + lane] = b1 + EPSV;
        // per-lane constant-column gathers, 16-deep pipeline
        const float* gp = yp + lab;
        float val[16];
        #pragma unroll
        for (int d = 0; d < 16; ++d) val[d] = gp[(size_t)(t0 + d) * CC];
        for (int c = 0; c < 16; ++c) {        // publish every 8 rows
            #pragma unroll
            for (int i = 0; i < 8; ++i) {
                const int r = 8 * c + i;
                float x = val[r & 15];
                if (r + 16 < 128) val[r & 15] = gp[(size_t)(t0 + r + 16) * CC];
                qtab[t0 + r][lane] = f16b(x + EPSV);
            }
            asm volatile("s_waitcnt lgkmcnt(0)" ::: "memory");
            if (lane == 0) *(volatile int*)&gatherDone[half] = 8 * c + 8;
        }
    } else if (wv >= 1) {
        // ============ streamers (waves 1..5): row sums only ============
        const int sw = wv - 1;                // 0..4, row-pairs r2 = sw + 5*i
        const int off = ((lane >> 5) << 7) + ((lane & 31) << 2);
        const float* base = yp + off;         // lanes 0-31 -> row 2*r2, 32-63 -> 2*r2+1
        float prodM = 1.0f;                   // product of mantissas (exact log accum)
        int   expS  = 0;                      // sum of exponents
        f32x4 v[8];
        #pragma unroll
        for (int d = 0; d < 8; ++d) {
            int r2 = sw + 5 * d; r2 = (r2 < 128) ? r2 : 127;
            v[d] = *(const f32x4*)(base + 256 * r2);
        }
        #pragma unroll
        for (int i = 0; i < 26; ++i) {
            const int  r2i   = sw + 5 * i;
            const bool valid = (r2i < 128);
            f32x4 x = v[i & 7];
            if (i + 8 < 26) {
                int rn = sw + 5 * (i + 8); rn = (rn < 128) ? rn : 127;
                v[i & 7] = *(const f32x4*)(base + 256 * rn);
            }
            // half-wave reduce: row-A total -> lane 31, row-B total -> lane 63
            float s = ((x[0] + x[1]) + (x[2] + x[3])) + 4.0f * EPSV;
            s += dpp0<0x111>(s);
            s += dpp0<0x112>(s);
            s += dpp0<0x114>(s);
            s += dpp0<0x118>(s);
            s += dpp0<0x142>(s);
            // log accumulation without transcendentals: s = m * 2^e, m in [1,2)
            unsigned bits = __float_as_uint(s);
            int   e    = (int)((bits >> 23) & 0xFF) - 127;
            float mant = __uint_as_float((bits & 0x007FFFFFu) | 0x3F800000u);
            if (valid) { prodM *= mant; expS += e; }   // prodM <= 2^26, no overflow
        }
        float zlog = __logf(prodM) + (float)expS * 0.69314718055994531f;
        float z31 = rdlane(zlog, 31), z63 = rdlane(zlog, 63);
        if (lane == 0) {
            logZpart[sw] = z31 + z63;
            asm volatile("s_waitcnt lgkmcnt(0)" ::: "memory");
            atomicAdd(&doneCnt, 1);
        }
    } else {
        // ============ wave 0: register DP, chasing the gather waves ============
        const int   labm1 = rol1_i(lab);
        const float mskip = (lane >= 1 && lab != labm1) ? 1.0f : 0.0f;
        const bool  l0 = (lane == 0);

        {   // wait for chunk 0 (rows 0..7 + qblank[0..127] ordering guaranteed)
            volatile int* g = &gatherDone[0];
            while (*g < 8) __builtin_amdgcn_s_sleep(1);
            __builtin_amdgcn_sched_barrier(0);
        }
        // t=0 init: alpha[0]=q0[blank], alpha[1]=q0[yt[0]], rest 0.
        float a0 = l0 ? qblank[0] : 0.0f;           // even state 2*lane
        float a1 = l0 ? h2f(qtab[0][lane]) : 0.0f;  // odd state 2*lane+1
        float aX = 0.0f;                             // state 128 (lane 0 only)
        int Esum = 0;

        {   // steps t = 1..7
            float qb8[8], ql8[8];
            #pragma unroll
            for (int i = 1; i < 8; ++i) { qb8[i] = qblank[i]; ql8[i] = h2f(qtab[i][lane]); }
            #pragma unroll
            for (int i = 1; i < 8; ++i) {
                float nb  = rol1_f(a1);              // alpha[2*lane-1]
                float na0 = (a0 + (l0 ? 0.0f : nb)) * qb8[i];
                float na1 = fmaf(mskip, nb, a0 + a1) * ql8[i];
                aX = l0 ? (aX + nb) * qb8[i] : 0.0f;
                a0 = na0; a1 = na1;
            }
            float mall = wave_max_bcast(fmaxf(fmaxf(a0, a1), aX));
            int e = 127 - (int)((__float_as_uint(mall) >> 23) & 0xFF);
            float sc = __uint_as_float((unsigned)(127 + e) << 23);
            a0 *= sc; a1 *= sc; aX *= sc;
            Esum += e;
        }
        for (int c = 1; c < 32; ++c) {               // chunks 1..31: steps 8c..8c+7
            const int half = c >> 4;
            const int need = ((c & 15) + 1) * 8;
            volatile int* g = &gatherDone[half];
            while (*g < need) __builtin_amdgcn_s_sleep(1);
            __builtin_amdgcn_sched_barrier(0);
            float qb8[8], ql8[8];
            #pragma unroll
            for (int i = 0; i < 8; ++i) {
                const int t = 8 * c + i;
                qb8[i] = qblank[t];
                ql8[i] = h2f(qtab[t][lane]);
            }
            #pragma unroll
            for (int i = 0; i < 8; ++i) {
                float nb  = rol1_f(a1);
                float na0 = (a0 + (l0 ? 0.0f : nb)) * qb8[i];
                float na1 = fmaf(mskip, nb, a0 + a1) * ql8[i];
                aX = l0 ? (aX + nb) * qb8[i] : 0.0f;
                a0 = na0; a1 = na1;
            }
            float mall = wave_max_bcast(fmaxf(fmaxf(a0, a1), aX));  // exact pow2 rescale
            int e = 127 - (int)((__float_as_uint(mall) >> 23) & 0xFF);
            float sc = __uint_as_float((unsigned)(127 + e) << 23);
            a0 *= sc; a1 *= sc; aX *= sc;
            Esum += e;
        }
        // wait for streamer logZ partials, sum in fixed order
        volatile int* vd = &doneCnt;
        while (*vd < 5) __builtin_amdgcn_s_sleep(1);
        __builtin_amdgcn_sched_barrier(0);
        float LZ = 0.0f;
        #pragma unroll
        for (int w = 0; w < 5; ++w) LZ += logZpart[w];
        float a127 = rdlane(a1, 63);
        if (lane == 0) {
            out[b] = LZ + (float)Esum * 0.69314718055994531f - __logf(aX + a127);
        }
    }
}

extern "C" void kernel_launch(void* const* d_in, const int* in_sizes, int n_in,
                              void* d_out, int out_size, void* d_ws, size_t ws_size,
                              hipStream_t stream) {
    const int*   y_true = (const int*)d_in[0];
    const float* y_pred = (const float*)d_in[1];
    float*       out    = (float*)d_out;
    ctc_fwd_kernel<<<BATCH, 512, 0, stream>>>(y_true, y_pred, out);
}

// Round 14
// 71.452 us; speedup vs baseline: 1.0036x; 1.0036x over previous
//
#include <hip/hip_runtime.h>
#include <math.h>

// CTC forward loss, Keras ctc_batch_cost semantics.
// B=1024, T=256, C=128, L=64, S=2L+1=129, blank=C-1=127.
// Prob-domain forward DP, exact power-of-2 rescale per 8-step chunk.
// Role split per block (512 thr):
//   waves 1-5 : stream y_pred (float4, 8-deep) computing ROW SUMS ONLY;
//               log(sum) accumulated as mantissa-product + exponent-sum
//               (one __logf per wave at the end, no per-row transcendental).
//   waves 6-7 : direct-gather qtab[t][l] = yp[t*128+lab_l] from global
//               (label column is per-lane constant -> no shuffles at all),
//               plus qblank; publish progress every 8 rows.
//   wave 0    : register DP, polling gather progress. Finishes ~with gathers,
//               hidden under the streaming time. No wave ever waits on DP.
#define BATCH 1024
#define TT    256
#define CC    128
#define LL    64
#define EPSV  (1e-7f)

typedef float f32x4 __attribute__((ext_vector_type(4)));

// DPP ctrl: row_shr:N = 0x110+N, row_bcast:15 = 0x142, row_bcast:31 = 0x143,
// wave_rol:1 = 0x134.
template <int CTRL>
__device__ __forceinline__ float dpp0(float x) {   // invalid lanes -> 0
    return __int_as_float(__builtin_amdgcn_update_dpp(0, __float_as_int(x), CTRL, 0xF, 0xF, true));
}
template <int CTRL>
__device__ __forceinline__ float dppS(float x) {   // invalid lanes -> self
    return __int_as_float(__builtin_amdgcn_update_dpp(__float_as_int(x), __float_as_int(x), CTRL, 0xF, 0xF, false));
}
__device__ __forceinline__ float rol1_f(float x) { // lane i <- lane (i-1)&63
    return __int_as_float(__builtin_amdgcn_update_dpp(__float_as_int(x), __float_as_int(x), 0x134, 0xF, 0xF, false));
}
__device__ __forceinline__ int rol1_i(int x) {
    return __builtin_amdgcn_update_dpp(x, x, 0x134, 0xF, 0xF, false);
}
__device__ __forceinline__ float rdlane(float x, int l) {
    return __int_as_float(__builtin_amdgcn_readlane(__float_as_int(x), l));
}
__device__ __forceinline__ float wave_max_bcast(float m) {
    m = fmaxf(m, dppS<0x111>(m));
    m = fmaxf(m, dppS<0x112>(m));
    m = fmaxf(m, dppS<0x114>(m));
    m = fmaxf(m, dppS<0x118>(m));
    m = fmaxf(m, dppS<0x142>(m));
    m = fmaxf(m, dppS<0x143>(m));
    return rdlane(m, 63);
}
__device__ __forceinline__ unsigned short f16b(float x) { // fp32 -> fp16 bits (RTN)
    _Float16 h = (_Float16)x;
    unsigned short u; __builtin_memcpy(&u, &h, 2);
    return u;
}
__device__ __forceinline__ float h2f(unsigned short u) {
    _Float16 h; __builtin_memcpy(&h, &u, 2);
    return (float)h;
}

__global__ __launch_bounds__(512, 8) void ctc_fwd_kernel(const int* __restrict__ y_true,
                                                         const float* __restrict__ y_pred,
                                                         float* __restrict__ out) {
    __shared__ unsigned short qtab[TT][64];  // q[t][l] = p[t][yt[l]]+eps (fp16 bits)
    __shared__ float qblank[TT];             // q[t][blank]
    __shared__ float logZpart[5];            // streamer partials (waves 1..5)
    __shared__ int   gatherDone[2];          // rows completed per half
    __shared__ int   doneCnt;                // finished streamers (5 when done)

    const int b    = blockIdx.x;
    const int tid  = threadIdx.x;
    const int wv   = tid >> 6;
    const int lane = tid & 63;

    const float* yp = y_pred + (size_t)b * (TT * CC);
    const int lab  = y_true[b * LL + lane];  // lane l holds label l (< 127 always)

    if (tid < 2) gatherDone[tid] = 0;
    if (tid == 2) doneCnt = 0;
    __syncthreads();

    if (wv >= 6) {
        // ============ gather waves: wv==7 -> rows 0..127, wv==6 -> rows 128..255 ============
        const int half = (wv == 7) ? 0 : 1;
        const int t0 = half * 128;
        // qblank first (strided loads, 2 instructions)
        float b0 = yp[(size_t)(t0 + lane) * CC + 127];
        float b1 = yp[(size_t)(t0 + 64 + lane) * CC + 127];
        qblank[t0 + lane]      = b0 + EPSV;
        qblank[t0 + 64 + lane] = b1 + EPSV;
        // per-lane constant-column gathers, 16-deep pipeline
        const float* gp = yp + lab;
        float val[16];
        #pragma unroll
        for (int d = 0; d < 16; ++d) val[d] = gp[(size_t)(t0 + d) * CC];
        for (int c = 0; c < 16; ++c) {        // publish every 8 rows
            #pragma unroll
            for (int i = 0; i < 8; ++i) {
                const int r = 8 * c + i;
                float x = val[r & 15];
                if (r + 16 < 128) val[r & 15] = gp[(size_t)(t0 + r + 16) * CC];
                qtab[t0 + r][lane] = f16b(x + EPSV);
            }
            asm volatile("s_waitcnt lgkmcnt(0)" ::: "memory");
            if (lane == 0) *(volatile int*)&gatherDone[half] = 8 * c + 8;
        }
    } else if (wv >= 1) {
        // ============ streamers (waves 1..5): row sums only ============
        const int sw = wv - 1;                // 0..4, row-pairs r2 = sw + 5*i
        const int off = ((lane >> 5) << 7) + ((lane & 31) << 2);
        const float* base = yp + off;         // lanes 0-31 -> row 2*r2, 32-63 -> 2*r2+1
        float prodM = 1.0f;                   // product of mantissas (exact log accum)
        int   expS  = 0;                      // sum of exponents
        f32x4 v[8];
        #pragma unroll
        for (int d = 0; d < 8; ++d) {
            int r2 = sw + 5 * d; r2 = (r2 < 128) ? r2 : 127;
            v[d] = *(const f32x4*)(base + 256 * r2);
        }
        #pragma unroll
        for (int i = 0; i < 26; ++i) {
            const int  r2i   = sw + 5 * i;
            const bool valid = (r2i < 128);
            f32x4 x = v[i & 7];
            if (i + 8 < 26) {
                int rn = sw + 5 * (i + 8); rn = (rn < 128) ? rn : 127;
                v[i & 7] = *(const f32x4*)(base + 256 * rn);
            }
            // half-wave reduce: row-A total -> lane 31, row-B total -> lane 63
            float s = ((x[0] + x[1]) + (x[2] + x[3])) + 4.0f * EPSV;
            s += dpp0<0x111>(s);
            s += dpp0<0x112>(s);
            s += dpp0<0x114>(s);
            s += dpp0<0x118>(s);
            s += dpp0<0x142>(s);
            // log accumulation without transcendentals: s = m * 2^e, m in [1,2)
            unsigned bits = __float_as_uint(s);
            int   e    = (int)((bits >> 23) & 0xFF) - 127;
            float mant = __uint_as_float((bits & 0x007FFFFFu) | 0x3F800000u);
            if (valid) { prodM *= mant; expS += e; }   // prodM <= 2^26, no overflow
        }
        float zlog = __logf(prodM) + (float)expS * 0.69314718055994531f;
        float z31 = rdlane(zlog, 31), z63 = rdlane(zlog, 63);
        if (lane == 0) {
            logZpart[sw] = z31 + z63;
            asm volatile("s_waitcnt lgkmcnt(0)" ::: "memory");
            atomicAdd(&doneCnt, 1);
        }
    } else {
        // ============ wave 0: register DP, chasing the gather waves ============
        const int   labm1 = rol1_i(lab);
        const float mskip = (lane >= 1 && lab != labm1) ? 1.0f : 0.0f;
        const bool  l0 = (lane == 0);

        {   // wait for chunk 0 (rows 0..7 + qblank[0..127] ordering guaranteed)
            volatile int* g = &gatherDone[0];
            while (*g < 8) __builtin_amdgcn_s_sleep(1);
            __builtin_amdgcn_sched_barrier(0);
        }
        // t=0 init: alpha[0]=q0[blank], alpha[1]=q0[yt[0]], rest 0.
        float a0 = l0 ? qblank[0] : 0.0f;           // even state 2*lane
        float a1 = l0 ? h2f(qtab[0][lane]) : 0.0f;  // odd state 2*lane+1
        float aX = 0.0f;                             // state 128 (lane 0 only)
        int Esum = 0;

        {   // steps t = 1..7
            float qb8[8], ql8[8];
            #pragma unroll
            for (int i = 1; i < 8; ++i) { qb8[i] = qblank[i]; ql8[i] = h2f(qtab[i][lane]); }
            #pragma unroll
            for (int i = 1; i < 8; ++i) {
                float nb  = rol1_f(a1);              // alpha[2*lane-1]
                float na0 = (a0 + (l0 ? 0.0f : nb)) * qb8[i];
                float na1 = fmaf(mskip, nb, a0 + a1) * ql8[i];
                aX = l0 ? (aX + nb) * qb8[i] : 0.0f;
                a0 = na0; a1 = na1;
            }
            float mall = wave_max_bcast(fmaxf(fmaxf(a0, a1), aX));
            int e = 127 - (int)((__float_as_uint(mall) >> 23) & 0xFF);
            float sc = __uint_as_float((unsigned)(127 + e) << 23);
            a0 *= sc; a1 *= sc; aX *= sc;
            Esum += e;
        }
        for (int c = 1; c < 32; ++c) {               // chunks 1..31: steps 8c..8c+7
            const int half = c >> 4;
            const int need = ((c & 15) + 1) * 8;
            volatile int* g = &gatherDone[half];
            while (*g < need) __builtin_amdgcn_s_sleep(1);
            __builtin_amdgcn_sched_barrier(0);
            float qb8[8], ql8[8];
            #pragma unroll
            for (int i = 0; i < 8; ++i) {
                const int t = 8 * c + i;
                qb8[i] = qblank[t];
                ql8[i] = h2f(qtab[t][lane]);
            }
            #pragma unroll
            for (int i = 0; i < 8; ++i) {
                float nb  = rol1_f(a1);
                float na0 = (a0 + (l0 ? 0.0f : nb)) * qb8[i];
                float na1 = fmaf(mskip, nb, a0 + a1) * ql8[i];
                aX = l0 ? (aX + nb) * qb8[i] : 0.0f;
                a0 = na0; a1 = na1;
            }
            float mall = wave_max_bcast(fmaxf(fmaxf(a0, a1), aX));  // exact pow2 rescale
            int e = 127 - (int)((__float_as_uint(mall) >> 23) & 0xFF);
            float sc = __uint_as_float((unsigned)(127 + e) << 23);
            a0 *= sc; a1 *= sc; aX *= sc;
            Esum += e;
        }
        // wait for streamer logZ partials, sum in fixed order
        volatile int* vd = &doneCnt;
        while (*vd < 5) __builtin_amdgcn_s_sleep(1);
        __builtin_amdgcn_sched_barrier(0);
        float LZ = 0.0f;
        #pragma unroll
        for (int w = 0; w < 5; ++w) LZ += logZpart[w];
        float a127 = rdlane(a1, 63);
        if (lane == 0) {
            out[b] = LZ + (float)Esum * 0.69314718055994531f - __logf(aX + a127);
        }
    }
}

extern "C" void kernel_launch(void* const* d_in, const int* in_sizes, int n_in,
                              void* d_out, int out_size, void* d_ws, size_t ws_size,
                              hipStream_t stream) {
    const int*   y_true = (const int*)d_in[0];
    const float* y_pred = (const float*)d_in[1];
    float*       out    = (float*)d_out;
    ctc_fwd_kernel<<<BATCH, 512, 0, stream>>>(y_true, y_pred, out);
}

// Round 15
// 36.495 us; speedup vs baseline: 1.9649x; 1.9578x over previous
//
#include <hip/hip_runtime.h>
#include <math.h>

// CTC forward loss, Keras ctc_batch_cost semantics.
// B=1024, T=256, C=128, L=64, S=2L+1=129, blank=C-1=127.
// Prob-domain forward DP (no per-step transcendentals), exact power-of-2
// rescale per 8-step chunk. Single kernel, producer-consumer:
//   waves 1-7 stream y_pred rows (float4 = 2 rows/load, 8-deep pipeline),
//   row sums via DPP half-wave reduce accumulated as mantissa-product +
//   exponent-sum (no per-row log), label gather via TWO ds_bpermute
//   (row-A data in lanes 0-31, row-B in 32-63 -> X/Y register trick),
//   one packed u32 LDS write per row-pair; publish chunk counters.
//   wave 0 runs the register DP concurrently, polling chunk counters.
// Streamers NEVER wait on the DP wave.
#define BATCH 1024
#define TT    256
#define CC    128
#define LL    64
#define EPSV  (1e-7f)

typedef float f32x4 __attribute__((ext_vector_type(4)));
typedef __fp16 fp16x2 __attribute__((ext_vector_type(2)));

// DPP ctrl: row_shr:N = 0x110+N, row_bcast:15 = 0x142, row_bcast:31 = 0x143,
// wave_rol:1 = 0x134.
template <int CTRL>
__device__ __forceinline__ float dpp0(float x) {   // invalid lanes -> 0
    return __int_as_float(__builtin_amdgcn_update_dpp(0, __float_as_int(x), CTRL, 0xF, 0xF, true));
}
template <int CTRL>
__device__ __forceinline__ float dppS(float x) {   // invalid lanes -> self
    return __int_as_float(__builtin_amdgcn_update_dpp(__float_as_int(x), __float_as_int(x), CTRL, 0xF, 0xF, false));
}
__device__ __forceinline__ float rol1_f(float x) { // lane i <- lane (i-1)&63
    return __int_as_float(__builtin_amdgcn_update_dpp(__float_as_int(x), __float_as_int(x), 0x134, 0xF, 0xF, false));
}
__device__ __forceinline__ int rol1_i(int x) {
    return __builtin_amdgcn_update_dpp(x, x, 0x134, 0xF, 0xF, false);
}
__device__ __forceinline__ float rdlane(float x, int l) {
    return __int_as_float(__builtin_amdgcn_readlane(__float_as_int(x), l));
}
__device__ __forceinline__ float wave_max_bcast(float m) {
    m = fmaxf(m, dppS<0x111>(m));
    m = fmaxf(m, dppS<0x112>(m));
    m = fmaxf(m, dppS<0x114>(m));
    m = fmaxf(m, dppS<0x118>(m));
    m = fmaxf(m, dppS<0x142>(m));
    m = fmaxf(m, dppS<0x143>(m));
    return rdlane(m, 63);
}
__device__ __forceinline__ int pkrtz(float a, float b) { // 2xf32 -> packed f16 (RTZ)
    fp16x2 h = __builtin_amdgcn_cvt_pkrtz(a, b);
    int r; __builtin_memcpy(&r, &h, 4);
    return r;
}
__device__ __forceinline__ float h2f(unsigned short u) {
    _Float16 h; __builtin_memcpy(&h, &u, 2);
    return (float)h;
}

__global__ __launch_bounds__(512, 8) void ctc_fwd_kernel(const int* __restrict__ y_true,
                                                         const float* __restrict__ y_pred,
                                                         float* __restrict__ out) {
    __shared__ unsigned qtab32[128][64];     // packed fp16 pair (q[2r2][l], q[2r2+1][l])
    __shared__ float qblank[TT];             // q[t][blank]
    __shared__ float logZpart[8];
    __shared__ int   chunkCnt[32];           // chunk c ready when == 4 (row-pairs 4c..4c+3)
    __shared__ int   doneCnt;                // streamer completion count (7 when done)

    const int b    = blockIdx.x;
    const int tid  = threadIdx.x;
    const int wv   = tid >> 6;
    const int lane = tid & 63;

    const float* yp = y_pred + (size_t)b * (TT * CC);
    const int lab  = y_true[b * LL + lane];  // lane l holds label l
    const int srcA = lab >> 2;               // 0..31
    const int srcB = 32 + srcA;
    const bool hiPair = (lab & 2) != 0;
    const bool hiHalf = (lab & 1) != 0;

    // float4 covers 2 rows: lanes 0-31 -> row 2*r2, lanes 32-63 -> row 2*r2+1.
    const int off = ((lane >> 5) << 7) + ((lane & 31) << 2);
    const float* base = yp + off;

    if (tid < 32) chunkCnt[tid] = 0;
    if (tid == 32) doneCnt = 0;
    __syncthreads();

    if (wv > 0) {
        // ================= streamers: waves 1-7, row-pairs r2 = (wv-1) + 7*i =================
        const int sw = wv - 1;               // 0..6
        float prodM = 1.0f;                  // mantissa product (meaningful lanes 31/63)
        int   expS  = 0;                     // exponent sum
        f32x4 v[8];
        #pragma unroll
        for (int d = 0; d < 8; ++d) {
            int r2 = sw + 7 * d; r2 = (r2 < 128) ? r2 : 127;
            v[d] = *(const f32x4*)(base + 256 * r2);
        }
        #pragma unroll
        for (int i = 0; i < 19; ++i) {
            const int  r2i   = sw + 7 * i;
            const bool valid = (r2i < 128);
            const int  r2    = valid ? r2i : 127;
            f32x4 x = v[i & 7];
            if (i + 8 < 19) {
                int rn = sw + 7 * (i + 8); rn = (rn < 128) ? rn : 127;
                v[i & 7] = *(const f32x4*)(base + 256 * rn);
            }
            float q0 = x[0] + EPSV, q1 = x[1] + EPSV;
            float q2 = x[2] + EPSV, q3 = x[3] + EPSV;
            // half-wave reduce: row-A total -> lane 31, row-B total -> lane 63
            float s = (q0 + q1) + (q2 + q3);
            s += dpp0<0x111>(s);
            s += dpp0<0x112>(s);
            s += dpp0<0x114>(s);
            s += dpp0<0x118>(s);
            s += dpp0<0x142>(s);
            // log accum without transcendentals: s = m * 2^e, m in [1,2)
            unsigned bits = __float_as_uint(s);
            if (valid) {
                expS += (int)((bits >> 23) & 0xFF) - 127;
                prodM *= __uint_as_float((bits & 0x007FFFFFu) | 0x3F800000u); // <= 2^19
            }
            // pack own 4 cols to fp16 pairs; 2-bpermute gather:
            //   X = rowA:i01 | rowB:i23,  Y = rowA:i23 | rowB:i01
            //   A = hiPair ? Y[srcA] : X[srcA];  B = hiPair ? X[srcB] : Y[srcB]
            int i01 = pkrtz(q0, q1);
            int i23 = pkrtz(q2, q3);
            int X = (lane < 32) ? i01 : i23;
            int Y = (lane < 32) ? i23 : i01;
            int u = __shfl(X, hiPair ? srcB : srcA);
            int w = __shfl(Y, hiPair ? srcA : srcB);
            int sA = hiPair ? w : u;
            int sB = hiPair ? u : w;
            unsigned hA = hiHalf ? ((unsigned)sA >> 16) : ((unsigned)sA & 0xFFFF);
            unsigned hB = hiHalf ? ((unsigned)sB >> 16) : ((unsigned)sB & 0xFFFF);
            if (valid) {
                qtab32[r2][lane] = hA | (hB << 16);
                if ((lane & 31) == 31) qblank[2 * r2 + (lane >> 5)] = q3; // col 127 == blank
                // make writes visible, then publish the row-pair
                asm volatile("s_waitcnt lgkmcnt(0)" ::: "memory");
                if (lane == 0) atomicAdd(&chunkCnt[r2 >> 2], 1);
            }
        }
        float zlog = __logf(prodM) + (float)expS * 0.69314718055994531f;
        float z31 = rdlane(zlog, 31), z63 = rdlane(zlog, 63);
        if (lane == 0) {
            logZpart[wv] = z31 + z63;
            asm volatile("s_waitcnt lgkmcnt(0)" ::: "memory");
            atomicAdd(&doneCnt, 1);
        }
    } else {
        // ================= wave 0: register DP, consuming chunks as published =================
        const int   labm1 = rol1_i(lab);
        const float mskip = (lane >= 1 && lab != labm1) ? 1.0f : 0.0f;
        const bool  l0 = (lane == 0);

        volatile int* vcnt = chunkCnt;
        // chunk 0: rows 0..7
        while (vcnt[0] < 4) __builtin_amdgcn_s_sleep(1);
        __builtin_amdgcn_sched_barrier(0);

        // t=0 init: alpha[0]=q0[blank], alpha[1]=q0[yt[0]], rest 0.
        float a0 = l0 ? qblank[0] : 0.0f;                              // even state 2*lane
        float a1 = l0 ? h2f((unsigned short)(qtab32[0][lane] & 0xFFFF)) : 0.0f;
        float aX = 0.0f;                                               // state 128 (lane 0)
        int Esum = 0;

        {   // steps t = 1..7 (rows in chunk 0)
            unsigned q4[4];
            #pragma unroll
            for (int j = 0; j < 4; ++j) q4[j] = qtab32[j][lane];
            float qb8[8], ql8[8];
            #pragma unroll
            for (int i = 1; i < 8; ++i) {
                qb8[i] = qblank[i];
                unsigned uu = q4[i >> 1];
                ql8[i] = h2f((unsigned short)((i & 1) ? (uu >> 16) : (uu & 0xFFFF)));
            }
            #pragma unroll
            for (int i = 1; i < 8; ++i) {
                float nb  = rol1_f(a1);              // alpha[2*lane-1]
                float na0 = (a0 + (l0 ? 0.0f : nb)) * qb8[i];
                float na1 = fmaf(mskip, nb, a0 + a1) * ql8[i];
                aX = l0 ? (aX + nb) * qb8[i] : 0.0f;
                a0 = na0; a1 = na1;
            }
            float mall = wave_max_bcast(fmaxf(fmaxf(a0, a1), aX));
            int e = 127 - (int)((__float_as_uint(mall) >> 23) & 0xFF);
            float sc = __uint_as_float((unsigned)(127 + e) << 23);
            a0 *= sc; a1 *= sc; aX *= sc;
            Esum += e;
        }
        for (int c = 1; c < 32; ++c) {               // chunks 1..31: steps 8c..8c+7
            while (vcnt[c] < 4) __builtin_amdgcn_s_sleep(1);
            __builtin_amdgcn_sched_barrier(0);
            unsigned q4[4];
            #pragma unroll
            for (int j = 0; j < 4; ++j) q4[j] = qtab32[4 * c + j][lane];
            float qb8[8], ql8[8];
            #pragma unroll
            for (int i = 0; i < 8; ++i) {
                qb8[i] = qblank[8 * c + i];
                unsigned uu = q4[i >> 1];
                ql8[i] = h2f((unsigned short)((i & 1) ? (uu >> 16) : (uu & 0xFFFF)));
            }
            #pragma unroll
            for (int i = 0; i < 8; ++i) {
                float nb  = rol1_f(a1);
                float na0 = (a0 + (l0 ? 0.0f : nb)) * qb8[i];
                float na1 = fmaf(mskip, nb, a0 + a1) * ql8[i];
                aX = l0 ? (aX + nb) * qb8[i] : 0.0f;
                a0 = na0; a1 = na1;
            }
            float mall = wave_max_bcast(fmaxf(fmaxf(a0, a1), aX));  // exact pow2 rescale
            int e = 127 - (int)((__float_as_uint(mall) >> 23) & 0xFF);
            float sc = __uint_as_float((unsigned)(127 + e) << 23);
            a0 *= sc; a1 *= sc; aX *= sc;
            Esum += e;
        }
        // wait for all logZ partials, sum in fixed order
        volatile int* vd = &doneCnt;
        while (*vd < 7) __builtin_amdgcn_s_sleep(1);
        __builtin_amdgcn_sched_barrier(0);
        float LZ = 0.0f;
        #pragma unroll
        for (int w = 1; w < 8; ++w) LZ += logZpart[w];
        float a127 = rdlane(a1, 63);
        if (lane == 0) {
            out[b] = LZ + (float)Esum * 0.69314718055994531f - __logf(aX + a127);
        }
    }
}

extern "C" void kernel_launch(void* const* d_in, const int* in_sizes, int n_in,
                              void* d_out, int out_size, void* d_ws, size_t ws_size,
                              hipStream_t stream) {
    const int*   y_true = (const int*)d_in[0];
    const float* y_pred = (const float*)d_in[1];
    float*       out    = (float*)d_out;
    ctc_fwd_kernel<<<BATCH, 512, 0, stream>>>(y_true, y_pred, out);
}